// Round 15
// baseline (395.373 us; speedup 1.0000x reference)
//
#include <hip/hip_runtime.h>
#include <hip/hip_bf16.h>

#define NK 1024        // codebook size
#define ND 64          // embedding dim
#define NV 131072      // 32*64*64 input vectors
#define BR 128         // rows per assign block (4 waves x 32 rows)
#define MARGIN 0.125f  // approx top-2 gap below which we re-solve exactly
#define DECAY_F 0.99f
#define OMD_F 0.01f
#define EPS_F 1e-5f
#define KEPS_F 0.01024f // fl32(1024 * 1e-5)

typedef const __attribute__((address_space(1))) void* gas1_t;
typedef __attribute__((address_space(3))) void* las3_t;
#define GLOAD_LDS16(gp, lp) \
    __builtin_amdgcn_global_load_lds((gas1_t)(gp), (las3_t)(lp), 16, 0, 0)

typedef __attribute__((ext_vector_type(8))) short bf16x8;
typedef __attribute__((ext_vector_type(4))) float f32x4;

__device__ __forceinline__ unsigned short f2bf(float f) {   // RNE f32->bf16
    unsigned u = __float_as_uint(f);
    u += 0x7FFFu + ((u >> 16) & 1u);
    return (unsigned short)(u >> 16);
}
__device__ __forceinline__ float bf2f(unsigned short h) {
    return __uint_as_float((unsigned)h << 16);
}

// ---- ws layout (bytes) ----
// 0       : csq[1024]     f32
// 4096    : cnt[1024]     i32
// 8192    : ucf[1024]     f32
// 12288   : loss          f64
// 12296   : nflag         i32
// 16384   : flaglist[NV]  i32   (512 KB, ends 540672)
// 540672  : frag[16384]   bf16x8 (256 KB, ends 802816)
// 802816  : acc[65536]    f32   (256 KB, ends 1064960)

// ---------------------------------------------------------------------------
// Kernel 1: prep — exact csq (numpy pairwise-8), split-bf16 B-fragment buffer
// (lane-ordered, so assign loads are 1KB coalesced), zero cnt/loss/nflag/acc.
// ---------------------------------------------------------------------------
__global__ __launch_bounds__(256) void vq_prep(const float* __restrict__ emb,
                                               float* __restrict__ csq,
                                               int* __restrict__ cnt,
                                               double* loss, int* nflag,
                                               float4* __restrict__ acc4,
                                               bf16x8* __restrict__ frag)
{
    const int g = blockIdx.x * 256 + threadIdx.x;   // 0..16383
    acc4[g] = make_float4(0.f, 0.f, 0.f, 0.f);
    if (g == 0) { *loss = 0.0; *nflag = 0; }

    if (g < NK) {                                   // exact codebook_sq
        cnt[g] = 0;
        float p[ND];
        const float4* e4 = reinterpret_cast<const float4*>(emb + (size_t)g * ND);
#pragma unroll
        for (int i = 0; i < 16; ++i) {
            float4 v = e4[i];
            p[4*i+0] = __fmul_rn(v.x, v.x);
            p[4*i+1] = __fmul_rn(v.y, v.y);
            p[4*i+2] = __fmul_rn(v.z, v.z);
            p[4*i+3] = __fmul_rn(v.w, v.w);
        }
        float r[8];
#pragma unroll
        for (int j = 0; j < 8; ++j) r[j] = p[j];
#pragma unroll
        for (int i = 8; i < ND; i += 8)
#pragma unroll
            for (int j = 0; j < 8; ++j) r[j] = __fadd_rn(r[j], p[i+j]);
        csq[g] = __fadd_rn(__fadd_rn(__fadd_rn(r[0], r[1]), __fadd_rn(r[2], r[3])),
                           __fadd_rn(__fadd_rn(r[4], r[5]), __fadd_rn(r[6], r[7])));
    }

    // B-fragment entry: g = ct*256 + f*64 + lane; f = part*2 + kt.
    // B layout: n = lane&15, k = (lane>>4)*8 + e.
    const int lane = g & 63, f = (g >> 6) & 3, ct = g >> 8;
    const int code = ct * 16 + (lane & 15);
    const int kt = f & 1, part = f >> 1;
    const int d0 = kt * 32 + ((lane >> 4) & 3) * 8;
    const float* er = emb + (size_t)code * ND;
    float4 a = *(const float4*)(er + d0);
    float4 b = *(const float4*)(er + d0 + 4);
    float v[8] = {a.x, a.y, a.z, a.w, b.x, b.y, b.z, b.w};
    bf16x8 s;
#pragma unroll
    for (int i = 0; i < 8; ++i) {
        unsigned short hi = f2bf(v[i]);
        unsigned short out = part ? f2bf(__fsub_rn(v[i], bf2f(hi))) : hi;
        s[i] = (short)out;
    }
    frag[g] = s;
}

// ---------------------------------------------------------------------------
// Kernel 2: MFMA assign, 2 row-tiles/wave. 128 rows/block, 4 waves x 32 rows.
// Per code-tile of 16: 4 frag loads feed 12 MFMAs (2 independent acc chains)
// -> half the L2 frag traffic per row, 2x MFMA ILP vs round 12. Top-2 margin
// tracking, flag -> exact fallback; full epilogue for non-flagged rows.
// ---------------------------------------------------------------------------
__global__ __launch_bounds__(256) void vq_assign(
    const float* __restrict__ x_in, const float* __restrict__ emb,
    const float* __restrict__ csq, const bf16x8* __restrict__ frag,
    float* __restrict__ out_qf, float* __restrict__ out_enc,
    float* __restrict__ acc_buf, int* __restrict__ cnt,
    double* __restrict__ loss_acc, int* __restrict__ nflag,
    int* __restrict__ flaglist)
{
    __shared__ __align__(16) float xsl[BR * ND];   // 32 KB, plain row-major
    __shared__ float csq_s[NK];                    // 4 KB
    __shared__ int bk_s[4][32];
    __shared__ double lds_ls[4];

    const int tid  = threadIdx.x;
    const int lane = tid & 63;
    const int wv   = tid >> 6;
    const size_t rowbase = (size_t)blockIdx.x * BR;
    const float4 zv = make_float4(0.f, 0.f, 0.f, 0.f);

    // stage x tile (linear DMA) + csq
#pragma unroll
    for (int c = 0; c < 8; ++c) {
        int f = tid + c * 256;
        GLOAD_LDS16(x_in + rowbase * ND + f * 4, &xsl[f * 4]);
    }
#pragma unroll
    for (int c = 0; c < 4; ++c) csq_s[tid + c * 256] = csq[tid + c * 256];
    __syncthreads();

    // A fragments, 2 row-tiles: row = wv*32 + rt*16 + (lane&15), k = (lane>>4)*8+e
    bf16x8 xh[2][2], xl[2][2];
#pragma unroll
    for (int rt = 0; rt < 2; ++rt) {
        const float* xrp = &xsl[(wv * 32 + rt * 16 + (lane & 15)) * ND];
        const int kb = ((lane >> 4) & 3) * 8;
#pragma unroll
        for (int kt = 0; kt < 2; ++kt) {
            float4 a = *(const float4*)(xrp + kt * 32 + kb);
            float4 b = *(const float4*)(xrp + kt * 32 + kb + 4);
            float v[8] = {a.x, a.y, a.z, a.w, b.x, b.y, b.z, b.w};
#pragma unroll
            for (int i = 0; i < 8; ++i) {
                unsigned short hi = f2bf(v[i]);
                xh[rt][kt][i] = (short)hi;
                xl[rt][kt][i] = (short)f2bf(__fsub_rn(v[i], bf2f(hi)));
            }
        }
    }

    float b1[2][4], b2[2][4]; int k1[2][4];
#pragma unroll
    for (int rt = 0; rt < 2; ++rt)
#pragma unroll
        for (int r = 0; r < 4; ++r) { b1[rt][r] = 3.4e38f; b2[rt][r] = 3.4e38f; k1[rt][r] = 0; }

    for (int ct = 0; ct < 64; ++ct) {
        bf16x8 eh0 = frag[(ct * 4 + 0) * 64 + lane];
        bf16x8 eh1 = frag[(ct * 4 + 1) * 64 + lane];
        bf16x8 el0 = frag[(ct * 4 + 2) * 64 + lane];
        bf16x8 el1 = frag[(ct * 4 + 3) * 64 + lane];
        float csqc = csq_s[ct * 16 + (lane & 15)];
        const int kcode = ct * 16 + (lane & 15);

        // two independent accumulation chains (ILP across row-tiles)
        f32x4 a0 = {0.f, 0.f, 0.f, 0.f};
        f32x4 a1 = {0.f, 0.f, 0.f, 0.f};
        a0 = __builtin_amdgcn_mfma_f32_16x16x32_bf16(xl[0][0], eh0, a0, 0, 0, 0);
        a1 = __builtin_amdgcn_mfma_f32_16x16x32_bf16(xl[1][0], eh0, a1, 0, 0, 0);
        a0 = __builtin_amdgcn_mfma_f32_16x16x32_bf16(xl[0][1], eh1, a0, 0, 0, 0);
        a1 = __builtin_amdgcn_mfma_f32_16x16x32_bf16(xl[1][1], eh1, a1, 0, 0, 0);
        a0 = __builtin_amdgcn_mfma_f32_16x16x32_bf16(xh[0][0], el0, a0, 0, 0, 0);
        a1 = __builtin_amdgcn_mfma_f32_16x16x32_bf16(xh[1][0], el0, a1, 0, 0, 0);
        a0 = __builtin_amdgcn_mfma_f32_16x16x32_bf16(xh[0][1], el1, a0, 0, 0, 0);
        a1 = __builtin_amdgcn_mfma_f32_16x16x32_bf16(xh[1][1], el1, a1, 0, 0, 0);
        a0 = __builtin_amdgcn_mfma_f32_16x16x32_bf16(xh[0][0], eh0, a0, 0, 0, 0);
        a1 = __builtin_amdgcn_mfma_f32_16x16x32_bf16(xh[1][0], eh0, a1, 0, 0, 0);
        a0 = __builtin_amdgcn_mfma_f32_16x16x32_bf16(xh[0][1], eh1, a0, 0, 0, 0);
        a1 = __builtin_amdgcn_mfma_f32_16x16x32_bf16(xh[1][1], eh1, a1, 0, 0, 0);

#pragma unroll
        for (int r = 0; r < 4; ++r) {               // D: col=lane&15, row=(lane>>4)*4+r
            float s0 = __builtin_fmaf(-2.f, a0[r], csqc);
            bool c0 = s0 < b1[0][r];
            float m0 = fminf(b2[0][r], s0);
            b2[0][r] = c0 ? b1[0][r] : m0;
            b1[0][r] = c0 ? s0 : b1[0][r];
            k1[0][r] = c0 ? kcode : k1[0][r];

            float s1 = __builtin_fmaf(-2.f, a1[r], csqc);
            bool c1 = s1 < b1[1][r];
            float m1 = fminf(b2[1][r], s1);
            b2[1][r] = c1 ? b1[1][r] : m1;
            b1[1][r] = c1 ? s1 : b1[1][r];
            k1[1][r] = c1 ? kcode : k1[1][r];
        }

        // enc zero-fill: 2 rows per code-tile, coalesced 4KB each
        float4* encb = reinterpret_cast<float4*>(out_enc + (rowbase + ct * 2) * NK);
        encb[tid]       = zv;
        encb[tid + 256] = zv;
    }

    // cross-lane top-2 merge within 16-lane groups (same l>>4)
#pragma unroll
    for (int rt = 0; rt < 2; ++rt)
#pragma unroll
    for (int r = 0; r < 4; ++r) {
        float b1r = b1[rt][r], b2r = b2[rt][r]; int k1r = k1[rt][r];
#pragma unroll
        for (int off = 1; off < 16; off <<= 1) {
            float pb1 = __shfl_xor(b1r, off, 64);
            float pb2 = __shfl_xor(b2r, off, 64);
            int   pk1 = __shfl_xor(k1r, off, 64);
            bool tp = (pb1 < b1r) || (pb1 == b1r && pk1 < k1r);
            float lose = tp ? b1r : pb1;
            b1r = tp ? pb1 : b1r;
            k1r = tp ? pk1 : k1r;
            b2r = fminf(fminf(b2r, pb2), lose);
        }
        b1[rt][r] = b1r; b2[rt][r] = b2r; k1[rt][r] = k1r;
    }

    if ((lane & 15) == 0) {
#pragma unroll
        for (int rt = 0; rt < 2; ++rt)
#pragma unroll
        for (int r = 0; r < 4; ++r) {
            int row = rt * 16 + ((lane >> 4) & 3) * 4 + r;  // wave-local 0..31
            bool fl = (b2[rt][r] - b1[rt][r]) < MARGIN;
            bk_s[wv][row] = fl ? -1 : k1[rt][r];
            if (fl) {
                int pos = atomicAdd(nflag, 1);
                flaglist[pos] = (int)(rowbase + wv * 32 + row);
            }
        }
    }
    asm volatile("s_waitcnt lgkmcnt(0)" ::: "memory");  // in-wave bk_s ready
    __builtin_amdgcn_sched_barrier(0);

    // epilogue for non-flagged rows (32 per wave)
    float lsum = 0.f;
    for (int rr = 0; rr < 32; ++rr) {
        int kr = bk_s[wv][rr];
        if (kr >= 0) {
            int rl = wv * 32 + rr;
            size_t grow = rowbase + rl;
            float xv = xsl[rl * ND + lane];
            float ev = emb[(size_t)kr * ND + lane];
            out_qf[grow * ND + lane] = __fadd_rn(xv, __fsub_rn(ev, xv));
            float dd = __fsub_rn(xv, ev);
            lsum = __builtin_fmaf(dd, dd, lsum);
            atomicAdd(&acc_buf[(size_t)kr * ND + lane], xv);
            if (lane == 0) atomicAdd(&cnt[kr], 1);
        }
    }
    double ls = (double)lsum;
#pragma unroll
    for (int off = 32; off >= 1; off >>= 1) ls += __shfl_xor(ls, off, 64);
    if (lane == 0) lds_ls[wv] = ls;

    // drain all zero-stores before the 1.0 scatter
    asm volatile("s_waitcnt vmcnt(0)" ::: "memory");
    __syncthreads();
    if (tid < BR) {
        int kr = bk_s[tid >> 5][tid & 31];
        if (kr >= 0) out_enc[(rowbase + tid) * NK + kr] = 1.0f;
    }
    if (tid == 0)
        atomicAdd(loss_acc, (lds_ls[0] + lds_ls[1]) + (lds_ls[2] + lds_ls[3]));
}

// ---------------------------------------------------------------------------
// Kernel 3: exact fallback — one wave per flagged row; serial-FMA distances
// (bit-identical to rounds 3-9), first-index tie-break; full row epilogue.
// ---------------------------------------------------------------------------
__global__ __launch_bounds__(256) void vq_fallback(
    const float* __restrict__ x_in, const float* __restrict__ emb,
    const float* __restrict__ csq, float* __restrict__ out_qf,
    float* __restrict__ out_enc, float* __restrict__ acc_buf,
    int* __restrict__ cnt, double* __restrict__ loss_acc,
    const int* __restrict__ nflag, const int* __restrict__ flaglist)
{
    __shared__ float xrow[4][ND];
    const int lane = threadIdx.x & 63;
    const int wv   = threadIdx.x >> 6;
    const int nf = *nflag;

    for (int i = blockIdx.x * 4 + wv; i < nf; i += 512 * 4) {
        const int row = flaglist[i];
        xrow[wv][lane] = x_in[(size_t)row * ND + lane];
        asm volatile("s_waitcnt lgkmcnt(0)" ::: "memory");
        __builtin_amdgcn_sched_barrier(0);

        float xr[ND];
#pragma unroll
        for (int d = 0; d < ND; ++d) xr[d] = xrow[wv][d];

        // exact isq (numpy pairwise-8)
        float r8[8];
#pragma unroll
        for (int j = 0; j < 8; ++j) r8[j] = __fmul_rn(xr[j], xr[j]);
#pragma unroll
        for (int g = 1; g < 8; ++g)
#pragma unroll
            for (int j = 0; j < 8; ++j)
                r8[j] = __fadd_rn(r8[j], __fmul_rn(xr[8*g+j], xr[8*g+j]));
        float isq = __fadd_rn(__fadd_rn(__fadd_rn(r8[0], r8[1]), __fadd_rn(r8[2], r8[3])),
                              __fadd_rn(__fadd_rn(r8[4], r8[5]), __fadd_rn(r8[6], r8[7])));

        float bd = 3.4e38f; int bk = 0;
        for (int c = 0; c < 16; ++c) {
            int kk = lane * 16 + c;
            const float4* e4 = reinterpret_cast<const float4*>(emb + (size_t)kk * ND);
            float dot = 0.f;
#pragma unroll
            for (int d4 = 0; d4 < 16; ++d4) {
                float4 ev = e4[d4];
                dot = __builtin_fmaf(xr[4*d4+0], ev.x, dot);
                dot = __builtin_fmaf(xr[4*d4+1], ev.y, dot);
                dot = __builtin_fmaf(xr[4*d4+2], ev.z, dot);
                dot = __builtin_fmaf(xr[4*d4+3], ev.w, dot);
            }
            float dist = __fsub_rn(__fadd_rn(isq, csq[kk]), __fmul_rn(2.0f, dot));
            if (dist < bd) { bd = dist; bk = kk; }   // c ascending -> first index
        }
#pragma unroll
        for (int off = 1; off < 64; off <<= 1) {
            float pd = __shfl_xor(bd, off, 64);
            int   pk = __shfl_xor(bk, off, 64);
            if (pd < bd || (pd == bd && pk < bk)) { bd = pd; bk = pk; }
        }

        float xv = xrow[wv][lane];
        float ev = emb[(size_t)bk * ND + lane];
        out_qf[(size_t)row * ND + lane] = __fadd_rn(xv, __fsub_rn(ev, xv));
        float dd = __fsub_rn(xv, ev);
        double ls = (double)__fmul_rn(dd, dd);
#pragma unroll
        for (int off = 32; off >= 1; off >>= 1) ls += __shfl_xor(ls, off, 64);
        atomicAdd(&acc_buf[(size_t)bk * ND + lane], xv);
        if (lane == 0) {
            atomicAdd(&cnt[bk], 1);
            out_enc[(size_t)row * NK + bk] = 1.0f;
            atomicAdd(loss_acc, ls);
        }
        asm volatile("s_waitcnt lgkmcnt(0)" ::: "memory");  // xrow reuse safe
    }
}

// ---------------------------------------------------------------------------
// Kernel 4: scan — uc (EMA counts), exact numpy-pairwise n, usage/loss, ucf.
// ---------------------------------------------------------------------------
__global__ __launch_bounds__(256) void vq_scan(
    const int* __restrict__ cnt, const float* __restrict__ ema_cs,
    const double* __restrict__ loss_acc, float* __restrict__ ucf_ws,
    float* __restrict__ out_uc, float* __restrict__ out_usage,
    float* __restrict__ out_loss)
{
    __shared__ float uc_s[1024];
    __shared__ int   usage_s;
    __shared__ float n_s;
    const int tid  = threadIdx.x;
    if (tid == 0) usage_s = 0;
    __syncthreads();

    int ucount = 0;
#pragma unroll
    for (int j = 0; j < 4; ++j) {
        int k = tid * 4 + j;
        int c = cnt[k];
        if (c > 0) ucount++;
        uc_s[k] = __fadd_rn(__fmul_rn(ema_cs[k], DECAY_F), __fmul_rn(OMD_F, (float)c));
    }
    atomicAdd(&usage_s, ucount);
    __syncthreads();

    if (tid < 64) {
        int b = tid >> 3, j = tid & 7;
        float r = uc_s[b * 128 + j];
#pragma unroll
        for (int i = 1; i < 16; ++i)
            r = __fadd_rn(r, uc_s[b * 128 + 8 * i + j]);
        r = __fadd_rn(r, __shfl_xor(r, 1, 64));
        r = __fadd_rn(r, __shfl_xor(r, 2, 64));
        r = __fadd_rn(r, __shfl_xor(r, 4, 64));
        r = __fadd_rn(r, __shfl_xor(r, 8, 64));
        r = __fadd_rn(r, __shfl_xor(r, 16, 64));
        r = __fadd_rn(r, __shfl_xor(r, 32, 64));
        if (tid == 0) {
            n_s = r;
            *out_usage = __fdiv_rn((float)usage_s, 1024.0f);
            *out_loss  = (float)(*loss_acc / 8388608.0);
        }
    }
    __syncthreads();

    const float n = n_s;
#pragma unroll
    for (int j = 0; j < 4; ++j) {
        int k = tid * 4 + j;
        float ucfv = __fmul_rn(__fdiv_rn(__fadd_rn(uc_s[k], EPS_F), __fadd_rn(n, KEPS_F)), n);
        out_uc[k] = ucfv;
        ucf_ws[k] = ucfv;
    }
}

// ---------------------------------------------------------------------------
// Kernel 5: final — upd_ema_w + upd_embeddings from acc.
// ---------------------------------------------------------------------------
__global__ __launch_bounds__(256) void vq_final(
    const float* __restrict__ acc_buf, const float* __restrict__ ema_w,
    const float* __restrict__ ucf, float* __restrict__ out_updw,
    float* __restrict__ out_upde)
{
    int gid = blockIdx.x * 256 + threadIdx.x;
    int k = gid >> 6;
    float w = __fadd_rn(__fmul_rn(ema_w[gid], DECAY_F), __fmul_rn(OMD_F, acc_buf[gid]));
    out_updw[gid] = w;
    out_upde[gid] = __fdiv_rn(w, __fadd_rn(ucf[k], EPS_F));
}

// ---------------------------------------------------------------------------
extern "C" void kernel_launch(void* const* d_in, const int* in_sizes, int n_in,
                              void* d_out, int out_size, void* d_ws, size_t ws_size,
                              hipStream_t stream)
{
    const float* x_in   = (const float*)d_in[0];
    const float* emb    = (const float*)d_in[1];
    const float* ema_cs = (const float*)d_in[2];
    const float* ema_w  = (const float*)d_in[3];

    float* out_qf    = (float*)d_out;                    // [NV*64]
    float* out_enc   = out_qf + (size_t)NV * ND;         // [NV*1024]
    float* out_usage = out_enc + (size_t)NV * NK;        // [1]
    float* out_loss  = out_usage + 1;                    // [1]
    float* out_upde  = out_loss + 1;                     // [1024*64]
    float* out_uc    = out_upde + (size_t)NK * ND;       // [1024]
    float* out_updw  = out_uc + NK;                      // [1024*64]

    char* ws = (char*)d_ws;
    float*  ws_csq   = (float*)(ws);
    int*    ws_cnt   = (int*)(ws + 4096);
    float*  ws_ucf   = (float*)(ws + 8192);
    double* ws_loss  = (double*)(ws + 12288);
    int*    ws_nflag = (int*)(ws + 12296);
    int*    ws_flag  = (int*)(ws + 16384);
    bf16x8* ws_frag  = (bf16x8*)(ws + 540672);
    float*  ws_acc   = (float*)(ws + 802816);

    vq_prep<<<64, 256, 0, stream>>>(emb, ws_csq, ws_cnt, ws_loss, ws_nflag,
                                    (float4*)ws_acc, ws_frag);
    vq_assign<<<NV / BR, 256, 0, stream>>>(x_in, emb, ws_csq, ws_frag, out_qf,
                                           out_enc, ws_acc, ws_cnt, ws_loss,
                                           ws_nflag, ws_flag);
    vq_fallback<<<512, 256, 0, stream>>>(x_in, emb, ws_csq, out_qf, out_enc,
                                         ws_acc, ws_cnt, ws_loss, ws_nflag, ws_flag);
    vq_scan<<<1, 256, 0, stream>>>(ws_cnt, ema_cs, ws_loss, ws_ucf,
                                   out_uc, out_usage, out_loss);
    vq_final<<<256, 256, 0, stream>>>(ws_acc, ema_w, ws_ucf, out_updw, out_upde);
}

// Round 16
// 300.096 us; speedup vs baseline: 1.3175x; 1.3175x over previous
//
#include <hip/hip_runtime.h>
#include <hip/hip_bf16.h>

#define NK 1024        // codebook size
#define ND 64          // embedding dim
#define NV 131072      // 32*64*64 input vectors
#define BR 128         // rows per assign block
#define DECAY_F 0.99f
#define OMD_F 0.01f
#define EPS_F 1e-5f
#define KEPS_F 0.01024f // fl32(1024 * 1e-5)

typedef const __attribute__((address_space(1))) void* gas1_t;
typedef __attribute__((address_space(3))) void* las3_t;
#define GLOAD_LDS16(gp, lp) \
    __builtin_amdgcn_global_load_lds((gas1_t)(gp), (las3_t)(lp), 16, 0, 0)

// ---- ws layout (bytes) ----
// 0       : csq[1024]    f32
// 4096    : cnt[1024]    i32
// 16384   : ucf[1024]    f32
// 20480   : loss         f64
// 1597440 : acc[65536]   f32 (256 KB)

// ---------------------------------------------------------------------------
// Kernel 1: codebook_sq (numpy pairwise-8 rounding); zero cnt/loss/acc.
// ---------------------------------------------------------------------------
__global__ __launch_bounds__(256) void vq_prep(const float* __restrict__ emb,
                                               float* __restrict__ csq,
                                               int* __restrict__ cnt,
                                               double* loss,
                                               float4* __restrict__ acc4)
{
    int k = blockIdx.x * 256 + threadIdx.x;
    cnt[k] = 0;
    if (k == 0) *loss = 0.0;
    float4 z = make_float4(0.f, 0.f, 0.f, 0.f);
#pragma unroll
    for (int i = 0; i < 16; ++i) acc4[k + i * 1024] = z;   // zero acc[65536]
    float p[ND];
    const float4* e4 = reinterpret_cast<const float4*>(emb + (size_t)k * ND);
#pragma unroll
    for (int i = 0; i < 16; ++i) {
        float4 v = e4[i];
        p[4*i+0] = __fmul_rn(v.x, v.x);
        p[4*i+1] = __fmul_rn(v.y, v.y);
        p[4*i+2] = __fmul_rn(v.z, v.z);
        p[4*i+3] = __fmul_rn(v.w, v.w);
    }
    float r[8];
#pragma unroll
    for (int j = 0; j < 8; ++j) r[j] = p[j];
#pragma unroll
    for (int i = 8; i < ND; i += 8)
#pragma unroll
        for (int j = 0; j < 8; ++j) r[j] = __fadd_rn(r[j], p[i+j]);
    csq[k] = __fadd_rn(__fadd_rn(__fadd_rn(r[0], r[1]), __fadd_rn(r[2], r[3])),
                       __fadd_rn(__fadd_rn(r[4], r[5]), __fadd_rn(r[6], r[7])));
}

// ---------------------------------------------------------------------------
// Kernel 2: register-tiled fp32 GEMM + fused argmin (round-8 structure).
// ONE change: block-parity tile stagger (odd blocks start at tile 4) to
// anti-phase co-resident blocks' barrier/DMA windows; inner compare gains an
// exact index tie-break so argmin is order-independent (distances themselves
// are bit-identical to rounds 3-9).
// ---------------------------------------------------------------------------
__global__ __launch_bounds__(256, 2) void vq_assign(
    const float* __restrict__ x_in, const float* __restrict__ emb,
    const float* __restrict__ csq, float* __restrict__ out_qf,
    float* __restrict__ out_enc, float* __restrict__ acc_buf,
    int* __restrict__ cnt, double* __restrict__ loss_acc)
{
    __shared__ __align__(16) float xs[BR * ND];    // 32 KB, swizzled
    __shared__ __align__(16) float es[128 * ND];   // 32 KB, swizzled
    __shared__ float csq_s[NK];
    __shared__ float isq_s[BR];
    __shared__ double lds_ls[4];

    const int tid  = threadIdx.x;
    const int lane = tid & 63;
    const int wv   = tid >> 6;
    const int tx   = tid & 15;
    const int ty   = tid >> 4;
    const int txs  = tx & 7;
    const int tys  = ty & 7;
    const int phase = (blockIdx.x & 1) << 2;   // 0 or 4: tile-order stagger
    const size_t rowbase = (size_t)blockIdx.x * BR;

    // ---- stage xs + es(tile `phase`) via async DMA; csq via regular copy ----
#pragma unroll
    for (int c = 0; c < 8; ++c) {
        int f = tid + c * 256;
        int row = f >> 4, ch = f & 15;
        int sch = ch ^ (row & 7);
        GLOAD_LDS16(x_in + rowbase * ND + row * ND + sch * 4, &xs[f * 4]);
    }
#pragma unroll
    for (int c = 0; c < 8; ++c) {
        int f = tid + c * 256;
        int row = f >> 4, ch = f & 15;
        int sch = ch ^ (row & 7);
        GLOAD_LDS16(emb + (size_t)phase * 128 * ND + (size_t)row * ND + sch * 4,
                    &es[f * 4]);
    }
#pragma unroll
    for (int c = 0; c < 4; ++c) csq_s[tid + c * 256] = csq[tid + c * 256];
    __syncthreads();

    // ---- isq per row (numpy pairwise-8 order, swizzled reads) ----
    if (tid < BR) {
        const int rs = tid & 7;
        const float* xr = &xs[tid * ND];
        float r[8];
        {
            float4 a = *(const float4*)&xr[(0 ^ rs) * 4];
            float4 b = *(const float4*)&xr[(1 ^ rs) * 4];
            r[0] = __fmul_rn(a.x, a.x); r[1] = __fmul_rn(a.y, a.y);
            r[2] = __fmul_rn(a.z, a.z); r[3] = __fmul_rn(a.w, a.w);
            r[4] = __fmul_rn(b.x, b.x); r[5] = __fmul_rn(b.y, b.y);
            r[6] = __fmul_rn(b.z, b.z); r[7] = __fmul_rn(b.w, b.w);
        }
#pragma unroll
        for (int g = 1; g < 8; ++g) {
            float4 a = *(const float4*)&xr[((2*g)   ^ rs) * 4];
            float4 b = *(const float4*)&xr[((2*g+1) ^ rs) * 4];
            r[0] = __fadd_rn(r[0], __fmul_rn(a.x, a.x));
            r[1] = __fadd_rn(r[1], __fmul_rn(a.y, a.y));
            r[2] = __fadd_rn(r[2], __fmul_rn(a.z, a.z));
            r[3] = __fadd_rn(r[3], __fmul_rn(a.w, a.w));
            r[4] = __fadd_rn(r[4], __fmul_rn(b.x, b.x));
            r[5] = __fadd_rn(r[5], __fmul_rn(b.y, b.y));
            r[6] = __fadd_rn(r[6], __fmul_rn(b.z, b.z));
            r[7] = __fadd_rn(r[7], __fmul_rn(b.w, b.w));
        }
        isq_s[tid] = __fadd_rn(__fadd_rn(__fadd_rn(r[0], r[1]), __fadd_rn(r[2], r[3])),
                               __fadd_rn(__fadd_rn(r[4], r[5]), __fadd_rn(r[6], r[7])));
    }

    float best[8];
    int   bestk[8];
#pragma unroll
    for (int i = 0; i < 8; ++i) { best[i] = 3.4e38f; bestk[i] = 0x7fffffff; }

    for (int t0 = 0; t0 < 8; ++t0) {
        const int t = (t0 + phase) & 7;   // current tile resident in es
        float acc[8][8];
#pragma unroll
        for (int i = 0; i < 8; ++i)
#pragma unroll
            for (int j = 0; j < 8; ++j) acc[i][j] = 0.f;

        for (int ch = 0; ch < 16; ++ch) {
            const int xo = (ch ^ tys) * 4;
            const int eo = (ch ^ txs) * 4;
            float4 xf[8], ef[8];
#pragma unroll
            for (int i = 0; i < 8; ++i)
                xf[i] = *(const float4*)&xs[(ty + 16*i) * ND + xo];
#pragma unroll
            for (int j = 0; j < 8; ++j)
                ef[j] = *(const float4*)&es[(tx + 16*j) * ND + eo];
#pragma unroll
            for (int i = 0; i < 8; ++i) {
#pragma unroll
                for (int j = 0; j < 8; ++j) {
                    float a = acc[i][j];
                    a = __builtin_fmaf(xf[i].x, ef[j].x, a);
                    a = __builtin_fmaf(xf[i].y, ef[j].y, a);
                    a = __builtin_fmaf(xf[i].z, ef[j].z, a);
                    a = __builtin_fmaf(xf[i].w, ef[j].w, a);
                    acc[i][j] = a;
                }
            }
        }

        // compare — explicit index tie-break makes argmin order-independent
#pragma unroll
        for (int i = 0; i < 8; ++i) {
            float isq = isq_s[ty + 16*i];
#pragma unroll
            for (int j = 0; j < 8; ++j) {
                float dist = __fsub_rn(__fadd_rn(isq, csq_s[t * 128 + tx + 16*j]),
                                       __fmul_rn(2.0f, acc[i][j]));
                int k = t * 128 + tx + 16*j;
                if (dist < best[i] || (dist == best[i] && k < bestk[i])) {
                    best[i] = dist; bestk[i] = k;
                }
            }
        }

        __syncthreads();            // all waves done reading es tile t
        if (t0 < 7) {
            const int tn = (t0 + 1 + phase) & 7;
#pragma unroll
            for (int c = 0; c < 8; ++c) {
                int f = tid + c * 256;
                int row = f >> 4, ch = f & 15;
                int sch = ch ^ (row & 7);
                GLOAD_LDS16(emb + (size_t)tn * 128 * ND + (size_t)row * ND + sch * 4,
                            &es[f * 4]);
            }
        }
        __syncthreads();            // DMA drained: next tile present
    }

    // ---- cross-thread argmin reduction (overlay scratch on es) ----
    float* red_d = es;
    int*   red_i = reinterpret_cast<int*>(es + 2048);
#pragma unroll
    for (int i = 0; i < 8; ++i) {
        red_d[(ty + 16*i) * 16 + tx] = best[i];
        red_i[(ty + 16*i) * 16 + tx] = bestk[i];
    }
    __syncthreads();
    if (tid < BR) {
        float bd = red_d[tid * 16];
        int   bk = red_i[tid * 16];
#pragma unroll
        for (int c = 1; c < 16; ++c) {
            float d  = red_d[tid * 16 + c];
            int   k2 = red_i[tid * 16 + c];
            if (d < bd || (d == bd && k2 < bk)) { bd = d; bk = k2; }
        }
        atomicAdd(&cnt[bk], 1);
        red_i[tid * 16] = bk;             // publish for epilogue
    }
    __syncthreads();

    // ---- epilogue: enc zero-fill + quantized_flow + loss + acc atomics,
    //      interleaved per row so stores drain under compute ----
    float lsum = 0.f;
    const int lsw = (lane >> 2);        // chunk of element `lane`
    const float4 zv = make_float4(0.f, 0.f, 0.f, 0.f);
    for (int r = 0; r < 32; ++r) {
        int rl = wv * 32 + r;
        int kr = red_i[rl * 16];
        size_t grow = rowbase + rl;
        // zero this row's encodings (4 coalesced 1KB stores, no wait)
        float4* dst = reinterpret_cast<float4*>(out_enc + grow * NK);
#pragma unroll
        for (int jj = 0; jj < 4; ++jj) dst[jj * 64 + lane] = zv;
        float xv = xs[rl * ND + ((lsw ^ (rl & 7)) << 2) + (lane & 3)];
        float ev = emb[(size_t)kr * ND + lane];
        out_qf[grow * ND + lane] = __fadd_rn(xv, __fsub_rn(ev, xv));
        float dd = __fsub_rn(xv, ev);
        lsum = __builtin_fmaf(dd, dd, lsum);
        atomicAdd(&acc_buf[(size_t)kr * ND + lane], xv);   // segment sum
    }
    double ls = (double)lsum;
#pragma unroll
    for (int off = 32; off >= 1; off >>= 1) ls += __shfl_xor(ls, off, 64);
    if (lane == 0) lds_ls[wv] = ls;

    // single drain: all zero-stores complete before the 1.0 scatter
    asm volatile("s_waitcnt vmcnt(0)" ::: "memory");
    __syncthreads();

    if (tid < BR) {
        int bk = red_i[tid * 16];
        out_enc[(rowbase + tid) * NK + bk] = 1.0f;
    }
    if (tid == 0)
        atomicAdd(loss_acc, (lds_ls[0] + lds_ls[1]) + (lds_ls[2] + lds_ls[3]));
}

// ---------------------------------------------------------------------------
// Kernel 3: scan — uc (EMA counts), exact numpy-pairwise n via one wave's
// shuffle tree, usage/loss scalars, ucf.
// ---------------------------------------------------------------------------
__global__ __launch_bounds__(256) void vq_scan(
    const int* __restrict__ cnt, const float* __restrict__ ema_cs,
    const double* __restrict__ loss_acc, float* __restrict__ ucf_ws,
    float* __restrict__ out_uc, float* __restrict__ out_usage,
    float* __restrict__ out_loss)
{
    __shared__ float uc_s[1024];
    __shared__ int   usage_s;
    __shared__ float n_s;
    const int tid  = threadIdx.x;
    if (tid == 0) usage_s = 0;
    __syncthreads();

    int ucount = 0;
#pragma unroll
    for (int j = 0; j < 4; ++j) {
        int k = tid * 4 + j;
        int c = cnt[k];
        if (c > 0) ucount++;
        uc_s[k] = __fadd_rn(__fmul_rn(ema_cs[k], DECAY_F), __fmul_rn(OMD_F, (float)c));
    }
    atomicAdd(&usage_s, ucount);
    __syncthreads();

    // exact numpy pairwise sum of uc_s[1024]: 8 blocks x 8 accumulators,
    // combined by a commutative-safe xor tree (j bits then b bits).
    if (tid < 64) {
        int b = tid >> 3, j = tid & 7;
        float r = uc_s[b * 128 + j];
#pragma unroll
        for (int i = 1; i < 16; ++i)
            r = __fadd_rn(r, uc_s[b * 128 + 8 * i + j]);
        r = __fadd_rn(r, __shfl_xor(r, 1, 64));
        r = __fadd_rn(r, __shfl_xor(r, 2, 64));
        r = __fadd_rn(r, __shfl_xor(r, 4, 64));
        r = __fadd_rn(r, __shfl_xor(r, 8, 64));
        r = __fadd_rn(r, __shfl_xor(r, 16, 64));
        r = __fadd_rn(r, __shfl_xor(r, 32, 64));
        if (tid == 0) {
            n_s = r;
            *out_usage = __fdiv_rn((float)usage_s, 1024.0f);
            *out_loss  = (float)(*loss_acc / 8388608.0);
        }
    }
    __syncthreads();

    const float n = n_s;
#pragma unroll
    for (int j = 0; j < 4; ++j) {
        int k = tid * 4 + j;
        float ucfv = __fmul_rn(__fdiv_rn(__fadd_rn(uc_s[k], EPS_F), __fadd_rn(n, KEPS_F)), n);
        out_uc[k] = ucfv;
        ucf_ws[k] = ucfv;
    }
}

// ---------------------------------------------------------------------------
// Kernel 4: final — upd_ema_w + upd_embeddings from acc.
// ---------------------------------------------------------------------------
__global__ __launch_bounds__(256) void vq_final(
    const float* __restrict__ acc_buf, const float* __restrict__ ema_w,
    const float* __restrict__ ucf, float* __restrict__ out_updw,
    float* __restrict__ out_upde)
{
    int gid = blockIdx.x * 256 + threadIdx.x;
    int k = gid >> 6;
    float w = __fadd_rn(__fmul_rn(ema_w[gid], DECAY_F), __fmul_rn(OMD_F, acc_buf[gid]));
    out_updw[gid] = w;
    out_upde[gid] = __fdiv_rn(w, __fadd_rn(ucf[k], EPS_F));
}

// ---------------------------------------------------------------------------
extern "C" void kernel_launch(void* const* d_in, const int* in_sizes, int n_in,
                              void* d_out, int out_size, void* d_ws, size_t ws_size,
                              hipStream_t stream)
{
    const float* x_in   = (const float*)d_in[0];
    const float* emb    = (const float*)d_in[1];
    const float* ema_cs = (const float*)d_in[2];
    const float* ema_w  = (const float*)d_in[3];

    float* out_qf    = (float*)d_out;                    // [NV*64]
    float* out_enc   = out_qf + (size_t)NV * ND;         // [NV*1024]
    float* out_usage = out_enc + (size_t)NV * NK;        // [1]
    float* out_loss  = out_usage + 1;                    // [1]
    float* out_upde  = out_loss + 1;                     // [1024*64]
    float* out_uc    = out_upde + (size_t)NK * ND;       // [1024]
    float* out_updw  = out_uc + NK;                      // [1024*64]

    char* ws = (char*)d_ws;
    float*  ws_csq    = (float*)(ws);
    int*    ws_cnt    = (int*)(ws + 4096);
    float*  ws_ucf    = (float*)(ws + 16384);
    double* ws_loss   = (double*)(ws + 20480);
    float*  ws_acc    = (float*)(ws + 1597440);

    vq_prep<<<4, 256, 0, stream>>>(emb, ws_csq, ws_cnt, ws_loss, (float4*)ws_acc);
    vq_assign<<<NV / BR, 256, 0, stream>>>(x_in, emb, ws_csq, out_qf, out_enc,
                                           ws_acc, ws_cnt, ws_loss);
    vq_scan<<<1, 256, 0, stream>>>(ws_cnt, ema_cs, ws_loss, ws_ucf,
                                   out_uc, out_usage, out_loss);
    vq_final<<<256, 256, 0, stream>>>(ws_acc, ema_w, ws_ucf, out_updw, out_upde);
}